// Round 14
// baseline (89.406 us; speedup 1.0000x reference)
//
#include <hip/hip_runtime.h>
#include <stdint.h>

#define N_SEQ 4096
#define MFMA16 __builtin_amdgcn_mfma_f32_16x16x32_bf16

typedef float f32x4 __attribute__((ext_vector_type(4)));
typedef float f32x2 __attribute__((ext_vector_type(2)));
typedef unsigned short u16x8 __attribute__((ext_vector_type(8)));
typedef unsigned short u16x4 __attribute__((ext_vector_type(4)));
typedef unsigned int u32x2 __attribute__((ext_vector_type(2)));
typedef __bf16 bf16x8 __attribute__((ext_vector_type(8)));

static __device__ __forceinline__ float bf2f(unsigned short u) {
    unsigned v = ((unsigned)u) << 16;
    return __builtin_bit_cast(float, v);
}

// ---------------- Kernel 0: repack W_qkv + W_proj -> bf16 fragment-ready (merged) ----------------
__global__ __launch_bounds__(256) void wrepack_kernel(
    const float* __restrict__ Wq, const float* __restrict__ Wp,
    unsigned short* __restrict__ WqF, unsigned short* __restrict__ WpF)
{
    int idx = blockIdx.x * 256 + threadIdx.x;   // [0, 65536)
    if (idx < 49152) {
        int i = idx & 7, l = (idx >> 3) & 63, fr = idx >> 9;
        int ct = fr >> 2, ks = fr & 3;
        int k = ks * 32 + (l >> 4) * 8 + i;
        int col = ct * 16 + (l & 15);
        WqF[idx] = __builtin_bit_cast(unsigned short, (__bf16)Wq[k * 384 + col]);
    } else {
        int j = idx - 49152;                    // [0, 16384)
        int i = j & 7, l = (j >> 3) & 63, fr = j >> 9;
        int ct = fr >> 2, ks = fr & 3;
        int k = ks * 32 + (l >> 4) * 8 + i;
        int col = ct * 16 + (l & 15);
        WpF[j] = __builtin_bit_cast(unsigned short, (__bf16)Wp[k * 128 + col]);
    }
}

// ---------------- Kernel 1: QKV projection via MFMA, 16 tokens/block ----------------
// Same fragment scheme / output layouts as the round-9 proven kernel; rt dimension
// removed (16 tokens), grid 1024 -> 4 waves/SIMD for latency hiding.
__global__ __launch_bounds__(256) void qkv_kernel(
    const float* __restrict__ x, const unsigned short* __restrict__ WqF,
    const float* __restrict__ bq, unsigned short* __restrict__ Qo,
    unsigned short* __restrict__ KFo, unsigned short* __restrict__ VFo)
{
    const int tid = threadIdx.x, lane = tid & 63, w = tid >> 6;
    const int g = lane >> 4, lo = lane & 15;
    const long r0 = (long)blockIdx.x * 16;
    const float SL = (float)(0.08838834764831845 * 1.4426950408889634);
    const f32x4 zf = {0.f, 0.f, 0.f, 0.f};

    bf16x8 xf[4];
    {
        const float* xr = x + (r0 + lo) * 128 + g * 8;
        #pragma unroll
        for (int ks = 0; ks < 4; ++ks) {
            f32x4 a = *(const f32x4*)&xr[ks * 32];
            f32x4 b = *(const f32x4*)&xr[ks * 32 + 4];
            bf16x8 f;
            f[0] = (__bf16)a[0]; f[1] = (__bf16)a[1]; f[2] = (__bf16)a[2]; f[3] = (__bf16)a[3];
            f[4] = (__bf16)b[0]; f[5] = (__bf16)b[1]; f[6] = (__bf16)b[2]; f[7] = (__bf16)b[3];
            xf[ks] = f;
        }
    }
    f32x4 acc[6];
    #pragma unroll
    for (int c = 0; c < 6; ++c) acc[c] = zf;

    const u16x8* wp = (const u16x8*)WqF + (size_t)(w * 24) * 64 + lane;
    #pragma unroll
    for (int c = 0; c < 6; ++c)
        #pragma unroll
        for (int ks = 0; ks < 4; ++ks) {
            bf16x8 wf = __builtin_bit_cast(bf16x8, wp[(c * 4 + ks) * 64]);
            acc[c] = MFMA16(xf[ks], wf, acc[c], 0, 0, 0);
        }

    // epilogue: D row = token r0 + 4g + j ; col fixed per c -> (h=w, d, s)
    const int bb = (int)(r0 >> 12), nn0 = (int)(r0 & 4095);
    const int bh = bb * 4 + w;
    const int t = nn0 >> 6, kvb = nn0 & 63;    // kvb in {0,16,32,48}
    const int kk = kvb >> 5;
    #pragma unroll
    for (int c = 0; c < 6; ++c) {
        int col = (w * 6 + c) * 16 + lo;
        int rem = col - w * 96;
        int d = rem / 3, s = rem % 3;
        float bias = bq[col];
        float scale = (s == 0) ? SL : 1.0f;
        unsigned short bits[4];
        #pragma unroll
        for (int j = 0; j < 4; ++j)
            bits[j] = __builtin_bit_cast(unsigned short,
                          (__bf16)((acc[c][j] + bias) * scale));
        if (s == 0) {
            long base = ((long)bh * 4096 + nn0 + 4 * g) * 32 + d;
            #pragma unroll
            for (int j = 0; j < 4; ++j) Qo[base + (long)j * 32] = bits[j];
        } else if (s == 1) {
            int ct_k = (kvb >> 4) & 3;         // kvi>>4 ; kvi&15 = 4g+j
            long base = (long)((bh * 64 + t) * 4 + ct_k) * 512
                      + ((d >> 3) * 16 + 4 * g) * 8 + (d & 7);
            #pragma unroll
            for (int j = 0; j < 4; ++j) KFo[base + j * 8] = bits[j];
        } else {
            int lg = ((kvb >> 3) & 3) | (g >> 1);  // (kvi>>3)&3, bit-disjoint parts
            long base = (long)(((bh * 64 + t) * 2 + kk) * 2 + (d >> 4)) * 512
                      + (lg * 16 + (d & 15)) * 8 + ((4 * g) & 7);
            u16x4 pk = {bits[0], bits[1], bits[2], bits[3]};
            *(u16x4*)&VFo[base] = pk;
        }
    }
}

// ---------------- Kernel 2: flash attention, kv-split x2, split-phase + V-prefetch ----------------
// vs round-13 proven kernel: V double-buffered again (load V(t+1) in body t) so
// L2 latency is covered by a full body; numerics byte-identical.
__global__ __launch_bounds__(256, 4) void attn_kernel(
    const unsigned short* __restrict__ Q, const unsigned short* __restrict__ KF,
    const unsigned short* __restrict__ VF, unsigned short* __restrict__ AO)
{
    __shared__ __align__(16) unsigned char smem[16384]; // P: 4 waves x 4KB; combine overlay 12KB

    const int tid = threadIdx.x, lane = tid & 63, w = tid >> 6;
    const int g = lane >> 4, lo = lane & 15;
    const int wq = w & 1, wh = w >> 1;

    // bijective XCD swizzle over 1024 blocks: each XCD owns 2 consecutive bh
    const int bid = blockIdx.x;
    const int vid = (bid & 7) * 128 + (bid >> 3);
    const int qi = vid & 63, bh = vid >> 6;
    const int q0 = qi * 64 + wq * 32;

    bf16x8 qf[2];
    #pragma unroll
    for (int rt = 0; rt < 2; ++rt) {
        const unsigned short* p = Q + ((long)bh * 4096 + q0 + rt * 16 + lo) * 32 + g * 8;
        qf[rt] = __builtin_bit_cast(bf16x8, *(const u16x8*)p);
    }
    bf16x8 onesf;
    {
        u16x8 ou = {0x3F80,0x3F80,0x3F80,0x3F80,0x3F80,0x3F80,0x3F80,0x3F80};
        onesf = __builtin_bit_cast(bf16x8, ou);
    }
    const f32x4 zf = {0.f, 0.f, 0.f, 0.f};
    f32x4 o_[2][2] = {{zf, zf}, {zf, zf}};
    f32x4 ls[2]    = {zf, zf};

    // P LDS layout (per wave, 32x64): P[q][kv] at q*64 + (((kv>>3) ^ (q&7))*8) + (kv&7)
    int woff[2][4], roff[2][2];
    #pragma unroll
    for (int qt = 0; qt < 2; ++qt) {
        int q = lo + 16 * qt;
        #pragma unroll
        for (int ct = 0; ct < 4; ++ct) {
            int kvb = 16 * ct + 4 * g;
            woff[qt][ct] = q * 64 + (((kvb >> 3) ^ (q & 7)) * 8) + ((kvb >> 2) & 1) * 4;
        }
    }
    #pragma unroll
    for (int rt = 0; rt < 2; ++rt) {
        int q = lo + 16 * rt;
        #pragma unroll
        for (int kk = 0; kk < 2; ++kk)
            roff[rt][kk] = q * 64 + ((((4 * kk) + g) ^ (q & 7)) * 8);
    }
    unsigned short* B = (unsigned short*)(smem + w * 4096);

    const u16x8* kp = (const u16x8*)KF + ((long)bh * 64 + wh * 32) * 256 + lane;
    const u16x8* vp = (const u16x8*)VF + ((long)bh * 64 + wh * 32) * 256 + lane;

    u16x8 K0[4], K1[4], V0[4], V1[4];
    #pragma unroll
    for (int i = 0; i < 4; ++i) { K0[i] = kp[i * 64]; V0[i] = vp[i * 64]; }
    kp += 256; vp += 256;

#define PACK2(S_, CT_)                                                          \
    do {                                                                        \
        unsigned a0 = __builtin_bit_cast(unsigned, __builtin_amdgcn_exp2f(S_[0][CT_][0]));\
        unsigned a1 = __builtin_bit_cast(unsigned, __builtin_amdgcn_exp2f(S_[0][CT_][1]));\
        unsigned a2 = __builtin_bit_cast(unsigned, __builtin_amdgcn_exp2f(S_[0][CT_][2]));\
        unsigned a3 = __builtin_bit_cast(unsigned, __builtin_amdgcn_exp2f(S_[0][CT_][3]));\
        u32x2 w0_;                                                              \
        w0_[0] = __builtin_amdgcn_perm(a1, a0, 0x07060302u);                    \
        w0_[1] = __builtin_amdgcn_perm(a3, a2, 0x07060302u);                    \
        *(u16x4*)&B[woff[0][CT_]] = __builtin_bit_cast(u16x4, w0_);             \
        unsigned c0 = __builtin_bit_cast(unsigned, __builtin_amdgcn_exp2f(S_[1][CT_][0]));\
        unsigned c1 = __builtin_bit_cast(unsigned, __builtin_amdgcn_exp2f(S_[1][CT_][1]));\
        unsigned c2 = __builtin_bit_cast(unsigned, __builtin_amdgcn_exp2f(S_[1][CT_][2]));\
        unsigned c3 = __builtin_bit_cast(unsigned, __builtin_amdgcn_exp2f(S_[1][CT_][3]));\
        u32x2 w1_;                                                              \
        w1_[0] = __builtin_amdgcn_perm(c1, c0, 0x07060302u);                    \
        w1_[1] = __builtin_amdgcn_perm(c3, c2, 0x07060302u);                    \
        *(u16x4*)&B[woff[1][CT_]] = __builtin_bit_cast(u16x4, w1_);             \
    } while (0)

#define PV(KK_, VC)                                                             \
    do {                                                                        \
        __builtin_amdgcn_s_setprio(1);                                          \
        _Pragma("unroll")                                                       \
        for (int rt = 0; rt < 2; ++rt) {                                        \
            bf16x8 paf = __builtin_bit_cast(bf16x8,                             \
                *(const u16x8*)&B[roff[rt][KK_]]);                              \
            ls[rt] = MFMA16(paf, onesf, ls[rt], 0, 0, 0);                       \
            o_[rt][0] = MFMA16(paf, __builtin_bit_cast(bf16x8, VC[KK_*2+0]),    \
                               o_[rt][0], 0, 0, 0);                             \
            o_[rt][1] = MFMA16(paf, __builtin_bit_cast(bf16x8, VC[KK_*2+1]),    \
                               o_[rt][1], 0, 0, 0);                             \
        }                                                                       \
        __builtin_amdgcn_s_setprio(0);                                          \
    } while (0)

// body t: prefetch K(t+1),V(t+1); QK(t) with KC; pack ct0,1 -> fence ->
//         PV(kk0,VC) + pack ct2,3 -> fence -> PV(kk1,VC) -> fence
#define BODY(KC, KN, VC, VN) do {                                              \
    _Pragma("unroll")                                                          \
    for (int i = 0; i < 4; ++i) KN[i] = kp[i * 64];                            \
    kp += 256;                                                                 \
    _Pragma("unroll")                                                          \
    for (int i = 0; i < 4; ++i) VN[i] = vp[i * 64];                            \
    vp += 256;                                                                 \
    f32x4 s_[2][4];                                                            \
    __builtin_amdgcn_s_setprio(1);                                             \
    _Pragma("unroll")                                                          \
    for (int ct = 0; ct < 4; ++ct) {                                           \
        bf16x8 kfr = __builtin_bit_cast(bf16x8, KC[ct]);                       \
        s_[0][ct] = MFMA16(kfr, qf[0], zf, 0, 0, 0);                           \
        s_[1][ct] = MFMA16(kfr, qf[1], zf, 0, 0, 0);                           \
    }                                                                          \
    __builtin_amdgcn_s_setprio(0);                                             \
    PACK2(s_, 0);                                                              \
    PACK2(s_, 1);                                                              \
    __builtin_amdgcn_sched_barrier(0);                                         \
    PV(0, VC);                                                                 \
    PACK2(s_, 2);                                                              \
    PACK2(s_, 3);                                                              \
    __builtin_amdgcn_sched_barrier(0);                                         \
    PV(1, VC);                                                                 \
    __builtin_amdgcn_sched_barrier(0);                                         \
} while (0)

    #pragma unroll 1
    for (int t = 0; t < 32; t += 2) {
        BODY(K0, K1, V0, V1);                // even t
        BODY(K1, K0, V1, V0);                // odd t+1 (t=31 prefetch overshoots: in-bounds ws)
    }
#undef BODY
#undef PV
#undef PACK2

    // ---- combine kv-halves (partials additive: no-max softmax) ----
    __syncthreads();                      // all P reads done before smem reuse
    float* sc = (float*)smem;             // 2 pairs x 64 lanes x 24 f32 = 12 KB
    float* myp = sc + (wq * 64 + lane) * 24;
    if (wh == 1) {
        #pragma unroll
        for (int rt = 0; rt < 2; ++rt)
            #pragma unroll
            for (int dt = 0; dt < 2; ++dt)
                *(f32x4*)&myp[(rt * 2 + dt) * 4] = o_[rt][dt];
        *(f32x4*)&myp[16] = ls[0];
        *(f32x4*)&myp[20] = ls[1];
    }
    __syncthreads();
    if (wh == 0) {
        #pragma unroll
        for (int rt = 0; rt < 2; ++rt) {
            #pragma unroll
            for (int dt = 0; dt < 2; ++dt)
                o_[rt][dt] += *(const f32x4*)&myp[(rt * 2 + dt) * 4];
            ls[rt] += *(const f32x4*)&myp[16 + rt * 4];
        }
        // epilogue: AO[b][n][h*32+d] bf16
        const int bb = bh >> 2, h = bh & 3;
        #pragma unroll
        for (int rt = 0; rt < 2; ++rt)
            #pragma unroll
            for (int j = 0; j < 4; ++j) {
                float rl = __builtin_amdgcn_rcpf(ls[rt][j]);
                int row = q0 + rt * 16 + 4 * g + j;
                #pragma unroll
                for (int dt = 0; dt < 2; ++dt) {
                    int e = h * 32 + lo + 16 * dt;
                    float val = o_[rt][dt][j] * rl;
                    AO[((long)bb * N_SEQ + row) * 128 + e] =
                        __builtin_bit_cast(unsigned short, (__bf16)val);
                }
            }
    }
}

// ---------------- Kernel 3: output projection via MFMA, 16 tokens/block ----------------
__global__ __launch_bounds__(256) void proj_kernel(
    const unsigned short* __restrict__ AO, const unsigned short* __restrict__ WpF,
    const float* __restrict__ bp, float* __restrict__ out)
{
    const int tid = threadIdx.x, lane = tid & 63, w = tid >> 6;
    const int g = lane >> 4, lo = lane & 15;
    const long r0 = (long)blockIdx.x * 16;
    const f32x4 zf = {0.f, 0.f, 0.f, 0.f};

    bf16x8 xf[4];
    {
        const unsigned short* xr = AO + (r0 + lo) * 128 + g * 8;
        #pragma unroll
        for (int ks = 0; ks < 4; ++ks)
            xf[ks] = __builtin_bit_cast(bf16x8, *(const u16x8*)&xr[ks * 32]);
    }
    f32x4 acc[2] = {zf, zf};

    const u16x8* wp = (const u16x8*)WpF + (size_t)(w * 8) * 64 + lane;
    #pragma unroll
    for (int c = 0; c < 2; ++c)
        #pragma unroll
        for (int ks = 0; ks < 4; ++ks) {
            bf16x8 wf = __builtin_bit_cast(bf16x8, wp[(c * 4 + ks) * 64]);
            acc[c] = MFMA16(xf[ks], wf, acc[c], 0, 0, 0);
        }

    // D: acc[c][j] = C[row r0+4g+j][col (w*2+c)*16+lo]
    #pragma unroll
    for (int c = 0; c < 2; ++c) {
        int col = (w * 2 + c) * 16 + lo;
        float bias = bp[col];
        long base = (r0 + 4 * g) * 128 + col;
        #pragma unroll
        for (int j = 0; j < 4; ++j)
            out[base + (long)j * 128] = acc[c][j] + bias;
    }
}

extern "C" void kernel_launch(void* const* d_in, const int* in_sizes, int n_in,
                              void* d_out, int out_size, void* d_ws, size_t ws_size,
                              hipStream_t stream)
{
    const float* x  = (const float*)d_in[0];
    const float* Wq = (const float*)d_in[1];
    const float* bq = (const float*)d_in[2];
    const float* Wp = (const float*)d_in[3];
    const float* bp = (const float*)d_in[4];
    float* out = (float*)d_out;

    // workspace: Q (4MB) | KF (4MB) | VF (4MB) | attn-out (4MB) | WqF (96KB) | WpF (32KB)
    unsigned short* Qw   = (unsigned short*)d_ws;
    unsigned short* KFw  = Qw   + (size_t)16 * 4096 * 32;
    unsigned short* VFw  = KFw  + (size_t)16 * 4096 * 32;
    unsigned short* AOw  = VFw  + (size_t)16 * 4096 * 32;
    unsigned short* WqFw = AOw  + (size_t)16 * 4096 * 32;
    unsigned short* WpFw = WqFw + (size_t)49152;

    wrepack_kernel<<<256, 256, 0, stream>>>(Wq, Wp, WqFw, WpFw);
    qkv_kernel<<<1024, 256, 0, stream>>>(x, WqFw, bq, Qw, KFw, VFw);
    attn_kernel<<<1024, 256, 0, stream>>>(Qw, KFw, VFw, AOw);
    proj_kernel<<<1024, 256, 0, stream>>>(AOw, WpFw, bp, out);
}

// Round 15
// 79.301 us; speedup vs baseline: 1.1274x; 1.1274x over previous
//
#include <hip/hip_runtime.h>
#include <stdint.h>

#define N_SEQ 4096
#define MFMA16 __builtin_amdgcn_mfma_f32_16x16x32_bf16

typedef float f32x4 __attribute__((ext_vector_type(4)));
typedef float f32x2 __attribute__((ext_vector_type(2)));
typedef unsigned short u16x8 __attribute__((ext_vector_type(8)));
typedef unsigned short u16x4 __attribute__((ext_vector_type(4)));
typedef unsigned int u32x2 __attribute__((ext_vector_type(2)));
typedef __bf16 bf16x8 __attribute__((ext_vector_type(8)));

static __device__ __forceinline__ float bf2f(unsigned short u) {
    unsigned v = ((unsigned)u) << 16;
    return __builtin_bit_cast(float, v);
}

// ---------------- Kernel 0: repack W_qkv + W_proj -> bf16 fragment-ready (round-14 proven) ----------------
__global__ __launch_bounds__(256) void wrepack_kernel(
    const float* __restrict__ Wq, const float* __restrict__ Wp,
    unsigned short* __restrict__ WqF, unsigned short* __restrict__ WpF)
{
    int idx = blockIdx.x * 256 + threadIdx.x;   // [0, 65536)
    if (idx < 49152) {
        int i = idx & 7, l = (idx >> 3) & 63, fr = idx >> 9;
        int ct = fr >> 2, ks = fr & 3;
        int k = ks * 32 + (l >> 4) * 8 + i;
        int col = ct * 16 + (l & 15);
        WqF[idx] = __builtin_bit_cast(unsigned short, (__bf16)Wq[k * 384 + col]);
    } else {
        int j = idx - 49152;                    // [0, 16384)
        int i = j & 7, l = (j >> 3) & 63, fr = j >> 9;
        int ct = fr >> 2, ks = fr & 3;
        int k = ks * 32 + (l >> 4) * 8 + i;
        int col = ct * 16 + (l & 15);
        WpF[j] = __builtin_bit_cast(unsigned short, (__bf16)Wp[k * 128 + col]);
    }
}

// ---------------- Kernel 1: QKV projection via MFMA, 16 tokens/block (round-14 proven) ----------------
__global__ __launch_bounds__(256) void qkv_kernel(
    const float* __restrict__ x, const unsigned short* __restrict__ WqF,
    const float* __restrict__ bq, unsigned short* __restrict__ Qo,
    unsigned short* __restrict__ KFo, unsigned short* __restrict__ VFo)
{
    const int tid = threadIdx.x, lane = tid & 63, w = tid >> 6;
    const int g = lane >> 4, lo = lane & 15;
    const long r0 = (long)blockIdx.x * 16;
    const float SL = (float)(0.08838834764831845 * 1.4426950408889634);
    const f32x4 zf = {0.f, 0.f, 0.f, 0.f};

    bf16x8 xf[4];
    {
        const float* xr = x + (r0 + lo) * 128 + g * 8;
        #pragma unroll
        for (int ks = 0; ks < 4; ++ks) {
            f32x4 a = *(const f32x4*)&xr[ks * 32];
            f32x4 b = *(const f32x4*)&xr[ks * 32 + 4];
            bf16x8 f;
            f[0] = (__bf16)a[0]; f[1] = (__bf16)a[1]; f[2] = (__bf16)a[2]; f[3] = (__bf16)a[3];
            f[4] = (__bf16)b[0]; f[5] = (__bf16)b[1]; f[6] = (__bf16)b[2]; f[7] = (__bf16)b[3];
            xf[ks] = f;
        }
    }
    f32x4 acc[6];
    #pragma unroll
    for (int c = 0; c < 6; ++c) acc[c] = zf;

    const u16x8* wp = (const u16x8*)WqF + (size_t)(w * 24) * 64 + lane;
    #pragma unroll
    for (int c = 0; c < 6; ++c)
        #pragma unroll
        for (int ks = 0; ks < 4; ++ks) {
            bf16x8 wf = __builtin_bit_cast(bf16x8, wp[(c * 4 + ks) * 64]);
            acc[c] = MFMA16(xf[ks], wf, acc[c], 0, 0, 0);
        }

    const int bb = (int)(r0 >> 12), nn0 = (int)(r0 & 4095);
    const int bh = bb * 4 + w;
    const int t = nn0 >> 6, kvb = nn0 & 63;    // kvb in {0,16,32,48}
    const int kk = kvb >> 5;
    #pragma unroll
    for (int c = 0; c < 6; ++c) {
        int col = (w * 6 + c) * 16 + lo;
        int rem = col - w * 96;
        int d = rem / 3, s = rem % 3;
        float bias = bq[col];
        float scale = (s == 0) ? SL : 1.0f;
        unsigned short bits[4];
        #pragma unroll
        for (int j = 0; j < 4; ++j)
            bits[j] = __builtin_bit_cast(unsigned short,
                          (__bf16)((acc[c][j] + bias) * scale));
        if (s == 0) {
            long base = ((long)bh * 4096 + nn0 + 4 * g) * 32 + d;
            #pragma unroll
            for (int j = 0; j < 4; ++j) Qo[base + (long)j * 32] = bits[j];
        } else if (s == 1) {
            int ct_k = (kvb >> 4) & 3;
            long base = (long)((bh * 64 + t) * 4 + ct_k) * 512
                      + ((d >> 3) * 16 + 4 * g) * 8 + (d & 7);
            #pragma unroll
            for (int j = 0; j < 4; ++j) KFo[base + j * 8] = bits[j];
        } else {
            int lg = ((kvb >> 3) & 3) | (g >> 1);
            long base = (long)(((bh * 64 + t) * 2 + kk) * 2 + (d >> 4)) * 512
                      + (lg * 16 + (d & 15)) * 8 + ((4 * g) & 7);
            u16x4 pk = {bits[0], bits[1], bits[2], bits[3]};
            *(u16x4*)&VFo[base] = pk;
        }
    }
}

// ---------------- Kernel 2: flash attention (round-13 proven version, verbatim) ----------------
// kv-split x2, V single-buffered in-body, P single-buffered, split-phase
// softmax/PV with setprio around MFMA clusters.
__global__ __launch_bounds__(256, 4) void attn_kernel(
    const unsigned short* __restrict__ Q, const unsigned short* __restrict__ KF,
    const unsigned short* __restrict__ VF, unsigned short* __restrict__ AO)
{
    __shared__ __align__(16) unsigned char smem[16384]; // P: 4 waves x 4KB; combine overlay 12KB

    const int tid = threadIdx.x, lane = tid & 63, w = tid >> 6;
    const int g = lane >> 4, lo = lane & 15;
    const int wq = w & 1, wh = w >> 1;

    // bijective XCD swizzle over 1024 blocks: each XCD owns 2 consecutive bh
    const int bid = blockIdx.x;
    const int vid = (bid & 7) * 128 + (bid >> 3);
    const int qi = vid & 63, bh = vid >> 6;
    const int q0 = qi * 64 + wq * 32;

    bf16x8 qf[2];
    #pragma unroll
    for (int rt = 0; rt < 2; ++rt) {
        const unsigned short* p = Q + ((long)bh * 4096 + q0 + rt * 16 + lo) * 32 + g * 8;
        qf[rt] = __builtin_bit_cast(bf16x8, *(const u16x8*)p);
    }
    bf16x8 onesf;
    {
        u16x8 ou = {0x3F80,0x3F80,0x3F80,0x3F80,0x3F80,0x3F80,0x3F80,0x3F80};
        onesf = __builtin_bit_cast(bf16x8, ou);
    }
    const f32x4 zf = {0.f, 0.f, 0.f, 0.f};
    f32x4 o_[2][2] = {{zf, zf}, {zf, zf}};
    f32x4 ls[2]    = {zf, zf};

    // P LDS layout (per wave, 32x64): P[q][kv] at q*64 + (((kv>>3) ^ (q&7))*8) + (kv&7)
    int woff[2][4], roff[2][2];
    #pragma unroll
    for (int qt = 0; qt < 2; ++qt) {
        int q = lo + 16 * qt;
        #pragma unroll
        for (int ct = 0; ct < 4; ++ct) {
            int kvb = 16 * ct + 4 * g;
            woff[qt][ct] = q * 64 + (((kvb >> 3) ^ (q & 7)) * 8) + ((kvb >> 2) & 1) * 4;
        }
    }
    #pragma unroll
    for (int rt = 0; rt < 2; ++rt) {
        int q = lo + 16 * rt;
        #pragma unroll
        for (int kk = 0; kk < 2; ++kk)
            roff[rt][kk] = q * 64 + ((((4 * kk) + g) ^ (q & 7)) * 8);
    }
    unsigned short* B = (unsigned short*)(smem + w * 4096);

    const u16x8* kp = (const u16x8*)KF + ((long)bh * 64 + wh * 32) * 256 + lane;
    const u16x8* vp = (const u16x8*)VF + ((long)bh * 64 + wh * 32) * 256 + lane;

    u16x8 K0[4], K1[4], Vb[4];
    #pragma unroll
    for (int i = 0; i < 4; ++i) K0[i] = kp[i * 64];   // K(first tile of half)
    kp += 256;

#define PACK2(S_, CT_)                                                          \
    do {                                                                        \
        unsigned a0 = __builtin_bit_cast(unsigned, __builtin_amdgcn_exp2f(S_[0][CT_][0]));\
        unsigned a1 = __builtin_bit_cast(unsigned, __builtin_amdgcn_exp2f(S_[0][CT_][1]));\
        unsigned a2 = __builtin_bit_cast(unsigned, __builtin_amdgcn_exp2f(S_[0][CT_][2]));\
        unsigned a3 = __builtin_bit_cast(unsigned, __builtin_amdgcn_exp2f(S_[0][CT_][3]));\
        u32x2 w0_;                                                              \
        w0_[0] = __builtin_amdgcn_perm(a1, a0, 0x07060302u);                    \
        w0_[1] = __builtin_amdgcn_perm(a3, a2, 0x07060302u);                    \
        *(u16x4*)&B[woff[0][CT_]] = __builtin_bit_cast(u16x4, w0_);             \
        unsigned c0 = __builtin_bit_cast(unsigned, __builtin_amdgcn_exp2f(S_[1][CT_][0]));\
        unsigned c1 = __builtin_bit_cast(unsigned, __builtin_amdgcn_exp2f(S_[1][CT_][1]));\
        unsigned c2 = __builtin_bit_cast(unsigned, __builtin_amdgcn_exp2f(S_[1][CT_][2]));\
        unsigned c3 = __builtin_bit_cast(unsigned, __builtin_amdgcn_exp2f(S_[1][CT_][3]));\
        u32x2 w1_;                                                              \
        w1_[0] = __builtin_amdgcn_perm(c1, c0, 0x07060302u);                    \
        w1_[1] = __builtin_amdgcn_perm(c3, c2, 0x07060302u);                    \
        *(u16x4*)&B[woff[1][CT_]] = __builtin_bit_cast(u16x4, w1_);             \
    } while (0)

#define PV(KK_)                                                                 \
    do {                                                                        \
        __builtin_amdgcn_s_setprio(1);                                          \
        _Pragma("unroll")                                                       \
        for (int rt = 0; rt < 2; ++rt) {                                        \
            bf16x8 paf = __builtin_bit_cast(bf16x8,                             \
                *(const u16x8*)&B[roff[rt][KK_]]);                              \
            ls[rt] = MFMA16(paf, onesf, ls[rt], 0, 0, 0);                       \
            o_[rt][0] = MFMA16(paf, __builtin_bit_cast(bf16x8, Vb[KK_*2+0]),    \
                               o_[rt][0], 0, 0, 0);                             \
            o_[rt][1] = MFMA16(paf, __builtin_bit_cast(bf16x8, Vb[KK_*2+1]),    \
                               o_[rt][1], 0, 0, 0);                             \
        }                                                                       \
        __builtin_amdgcn_s_setprio(0);                                          \
    } while (0)

#define BODY(KC, KN) do {                                                      \
    _Pragma("unroll")                                                          \
    for (int i = 0; i < 4; ++i) KN[i] = kp[i * 64];                            \
    kp += 256;                                                                 \
    _Pragma("unroll")                                                          \
    for (int i = 0; i < 4; ++i) Vb[i] = vp[i * 64];                            \
    vp += 256;                                                                 \
    f32x4 s_[2][4];                                                            \
    __builtin_amdgcn_s_setprio(1);                                             \
    _Pragma("unroll")                                                          \
    for (int ct = 0; ct < 4; ++ct) {                                           \
        bf16x8 kfr = __builtin_bit_cast(bf16x8, KC[ct]);                       \
        s_[0][ct] = MFMA16(kfr, qf[0], zf, 0, 0, 0);                           \
        s_[1][ct] = MFMA16(kfr, qf[1], zf, 0, 0, 0);                           \
    }                                                                          \
    __builtin_amdgcn_s_setprio(0);                                             \
    PACK2(s_, 0);                                                              \
    PACK2(s_, 1);                                                              \
    __builtin_amdgcn_sched_barrier(0);                                         \
    PV(0);                                                                     \
    PACK2(s_, 2);                                                              \
    PACK2(s_, 3);                                                              \
    __builtin_amdgcn_sched_barrier(0);                                         \
    PV(1);                                                                     \
    __builtin_amdgcn_sched_barrier(0);                                         \
} while (0)

    #pragma unroll 1
    for (int t = 0; t < 32; t += 2) {
        BODY(K0, K1);                        // even t
        BODY(K1, K0);                        // odd t+1 (t=31 K-prefetch overshoots: in-bounds ws)
    }
#undef BODY
#undef PV
#undef PACK2

    // ---- combine kv-halves (partials additive: no-max softmax) ----
    __syncthreads();                      // all P reads done before smem reuse
    float* sc = (float*)smem;             // 2 pairs x 64 lanes x 24 f32 = 12 KB
    float* myp = sc + (wq * 64 + lane) * 24;
    if (wh == 1) {
        #pragma unroll
        for (int rt = 0; rt < 2; ++rt)
            #pragma unroll
            for (int dt = 0; dt < 2; ++dt)
                *(f32x4*)&myp[(rt * 2 + dt) * 4] = o_[rt][dt];
        *(f32x4*)&myp[16] = ls[0];
        *(f32x4*)&myp[20] = ls[1];
    }
    __syncthreads();
    if (wh == 0) {
        #pragma unroll
        for (int rt = 0; rt < 2; ++rt) {
            #pragma unroll
            for (int dt = 0; dt < 2; ++dt)
                o_[rt][dt] += *(const f32x4*)&myp[(rt * 2 + dt) * 4];
            ls[rt] += *(const f32x4*)&myp[16 + rt * 4];
        }
        // epilogue: AO[b][n][h*32+d] bf16
        const int bb = bh >> 2, h = bh & 3;
        #pragma unroll
        for (int rt = 0; rt < 2; ++rt)
            #pragma unroll
            for (int j = 0; j < 4; ++j) {
                float rl = __builtin_amdgcn_rcpf(ls[rt][j]);
                int row = q0 + rt * 16 + 4 * g + j;
                #pragma unroll
                for (int dt = 0; dt < 2; ++dt) {
                    int e = h * 32 + lo + 16 * dt;
                    float val = o_[rt][dt][j] * rl;
                    AO[((long)bb * N_SEQ + row) * 128 + e] =
                        __builtin_bit_cast(unsigned short, (__bf16)val);
                }
            }
    }
}

// ---------------- Kernel 3: output projection via MFMA, 16 tokens/block (round-14 proven) ----------------
__global__ __launch_bounds__(256) void proj_kernel(
    const unsigned short* __restrict__ AO, const unsigned short* __restrict__ WpF,
    const float* __restrict__ bp, float* __restrict__ out)
{
    const int tid = threadIdx.x, lane = tid & 63, w = tid >> 6;
    const int g = lane >> 4, lo = lane & 15;
    const long r0 = (long)blockIdx.x * 16;
    const f32x4 zf = {0.f, 0.f, 0.f, 0.f};

    bf16x8 xf[4];
    {
        const unsigned short* xr = AO + (r0 + lo) * 128 + g * 8;
        #pragma unroll
        for (int ks = 0; ks < 4; ++ks)
            xf[ks] = __builtin_bit_cast(bf16x8, *(const u16x8*)&xr[ks * 32]);
    }
    f32x4 acc[2] = {zf, zf};

    const u16x8* wp = (const u16x8*)WpF + (size_t)(w * 8) * 64 + lane;
    #pragma unroll
    for (int c = 0; c < 2; ++c)
        #pragma unroll
        for (int ks = 0; ks < 4; ++ks) {
            bf16x8 wf = __builtin_bit_cast(bf16x8, wp[(c * 4 + ks) * 64]);
            acc[c] = MFMA16(xf[ks], wf, acc[c], 0, 0, 0);
        }

    #pragma unroll
    for (int c = 0; c < 2; ++c) {
        int col = (w * 2 + c) * 16 + lo;
        float bias = bp[col];
        long base = (r0 + 4 * g) * 128 + col;
        #pragma unroll
        for (int j = 0; j < 4; ++j)
            out[base + (long)j * 128] = acc[c][j] + bias;
    }
}

extern "C" void kernel_launch(void* const* d_in, const int* in_sizes, int n_in,
                              void* d_out, int out_size, void* d_ws, size_t ws_size,
                              hipStream_t stream)
{
    const float* x  = (const float*)d_in[0];
    const float* Wq = (const float*)d_in[1];
    const float* bq = (const float*)d_in[2];
    const float* Wp = (const float*)d_in[3];
    const float* bp = (const float*)d_in[4];
    float* out = (float*)d_out;

    // workspace: Q (4MB) | KF (4MB) | VF (4MB) | attn-out (4MB) | WqF (96KB) | WpF (32KB)
    unsigned short* Qw   = (unsigned short*)d_ws;
    unsigned short* KFw  = Qw   + (size_t)16 * 4096 * 32;
    unsigned short* VFw  = KFw  + (size_t)16 * 4096 * 32;
    unsigned short* AOw  = VFw  + (size_t)16 * 4096 * 32;
    unsigned short* WqFw = AOw  + (size_t)16 * 4096 * 32;
    unsigned short* WpFw = WqFw + (size_t)49152;

    wrepack_kernel<<<256, 256, 0, stream>>>(Wq, Wp, WqFw, WpFw);
    qkv_kernel<<<1024, 256, 0, stream>>>(x, WqFw, bq, Qw, KFw, VFw);
    attn_kernel<<<1024, 256, 0, stream>>>(Qw, KFw, VFw, AOw);
    proj_kernel<<<1024, 256, 0, stream>>>(AOw, WpFw, bp, out);
}